// Round 1
// baseline (174.718 us; speedup 1.0000x reference)
//
#include <hip/hip_runtime.h>
#include <math.h>

#define BATCH 32
#define NGT 20
#define HWA 10647
#define NCLS 80
#define FP16_EPS 0.0009765625f
#define BCE_EPS 1e-6f

__device__ __constant__ float ANCS[9][2] = {
    {0.024f, 0.031f}, {0.038f, 0.072f}, {0.079f, 0.055f},
    {0.072f, 0.147f}, {0.149f, 0.108f}, {0.142f, 0.286f},
    {0.279f, 0.216f}, {0.375f, 0.476f}, {0.897f, 0.784f}};

// Matching state per HWA row, packed into one int resolved by atomicMax:
//   bits [31:16] = priority (2p+1 for the "-1" col0 write, 2p+2 for the
//                  positive full-row write at scan step p)
//   bit  [15]    = is-positive-write
//   bits [7:0]   = rec = i*9 + a  (GT index i, anchor id a) — the full 90-wide
//                  target row t is a pure function of (i,a), so this is all we
//                  need to reconstruct it for positive rows.
// cell == 0  <=>  never written  <=>  gconf == 0 (negative row).
// Last-writer-wins semantics of the reference's sequential scan are preserved
// because priorities are strictly increasing in scan order, and within a step
// the positive write (2p+2) beats that step's -1 write (2p+1).

__global__ __launch_bounds__(256) void yolo_main(
    const float* __restrict__ pconf,   // [B, HWA, 1]
    const float* __restrict__ pcls,    // [B, HWA, 80]
    const float* __restrict__ ptxywh,  // [B, HWA, 4]
    const float* __restrict__ gbox,    // [B, NGT, 4]
    const int* __restrict__ glab,      // [B, NGT]
    float* __restrict__ part)          // [B, 8] partials
{
  const int b = blockIdx.x;
  const int tid = threadIdx.x;

  __shared__ int cell[HWA];
  __shared__ int pos_list[256];
  __shared__ float s_cx[NGT], s_cy[NGT], s_w[NGT], s_h[NGT], s_wt[NGT];
  __shared__ int s_a[NGT], s_lab[NGT], s_idx[NGT][3];
  __shared__ int s_np;
  __shared__ float red[4][8];

  // ---- init + per-GT precompute (identical f32 op order as reference) ----
  for (int r = tid; r < HWA; r += 256) cell[r] = 0;
  if (tid == 0) s_np = 0;
  if (tid < NGT) {
    const float* gb = gbox + (b * NGT + tid) * 4;
    float l = gb[0], t = gb[1], r = gb[2], bo = gb[3];
    float cx = (l + r) * 0.5f, cy = (t + bo) * 0.5f;
    float w = r - l, h = bo - t;
    s_cx[tid] = cx; s_cy[tid] = cy; s_w[tid] = w; s_h[tid] = h;
    s_wt[tid] = 2.0f - w * h;
    s_lab[tid] = glab[b * NGT + tid];
    float best = -1e30f; int bi = 0;
    for (int a = 0; a < 9; ++a) {
      float inter = fminf(w, ANCS[a][0]) * fminf(h, ANCS[a][1]);
      float uni = w * h + ANCS[a][0] * ANCS[a][1] - inter;
      float ratio = inter / uni;
      if (ratio > best) { best = ratio; bi = a; }  // first max, like argmax
    }
    s_a[tid] = bi;
    const int GR[3] = {52, 26, 13};
    const int OF[3] = {0, 2704, 3380};
    for (int j = 0; j < 3; ++j) {
      int col = (int)(cx * (float)GR[j]);   // trunc, matches astype(int32)
      int row = (int)(cy * (float)GR[j]);
      s_idx[tid][j] = (OF[j] + row * GR[j] + col) * 3;
    }
  }
  __syncthreads();

  // ---- the 400-step scan, parallelized via priority atomicMax ----
  for (int p = tid; p < NGT * NGT; p += 256) {
    int i = p / NGT, k = p - i * NGT;
    int a = s_a[k];
    int ceng = a / 3;
    int pn = (2 * p + 1) << 16;
    int pp = ((2 * p + 2) << 16) | (1 << 15) | (i * 9 + a);
    for (int j = 0; j < 3; ++j) {
      int idx = s_idx[i][j];
      atomicMax(&cell[idx], pn);
      atomicMax(&cell[idx + 1], pn);
      atomicMax(&cell[idx + 2], pn);
      if (ceng == j) atomicMax(&cell[idx + (a - ceng * 3)], pp);
    }
  }
  __syncthreads();

  // ---- dense pconf pass + positive-row compaction ----
  float sum_pos = 0.f, sum_neg = 0.f;
  int cnt_pos = 0, cnt_neg = 0;
  for (int r = tid; r < HWA; r += 256) {
    int c = cell[r];
    float x = pconf[(size_t)b * HWA + r];
    float s = 1.0f / (1.0f + expf(-x));
    if (c == 0) {                      // gconf == 0
      sum_neg += s * s; cnt_neg++;
    } else if (c & (1 << 15)) {        // gconf == 1
      float d = s - 1.0f; sum_pos += d * d; cnt_pos++;
      int slot = atomicAdd(&s_np, 1);
      if (slot < 256) pos_list[slot] = ((c & 0xFF) << 16) | r;
    }                                  // else gconf == -1: ignored
  }
  __syncthreads();
  int P = s_np;

  // ---- sparse class BCE over positive rows (P*80 work items) ----
  float cls_sum = 0.f;
  for (int idx = tid; idx < P * NCLS; idx += 256) {
    int pr = idx / NCLS, c = idx - pr * NCLS;
    int pk = pos_list[pr];
    int r = pk & 0xFFFF, rec = pk >> 16;
    int i = rec / 9;
    int lab = s_lab[i] - 1;
    float x = pcls[((size_t)b * HWA + r) * NCLS + c];
    float s = 1.0f / (1.0f + expf(-x));
    s = fminf(fmaxf(s, BCE_EPS), 1.0f - BCE_EPS);
    float g = (c == lab) ? 1.0f : 0.0f;
    cls_sum += -(g * logf(s) + (1.0f - g) * logf(1.0f - s));
  }

  // ---- sparse txty (BCE) + twth (L2) over positive rows ----
  float txty_sum = 0.f, twth_sum = 0.f;
  for (int q = tid; q < P; q += 256) {
    int pk = pos_list[q];
    int r = pk & 0xFFFF, rec = pk >> 16;
    int i = rec / 9, a = rec - i * 9;
    int ceng = a / 3;
    const int GR[3] = {52, 26, 13};
    float grid = (float)GR[ceng];
    float cx = s_cx[i], cy = s_cy[i];
    int col = (int)(cx * grid), row = (int)(cy * grid);
    float tx = (cx - (float)col / grid) * grid;
    float ty = (cy - (float)row / grid) * grid;
    float twx = logf(s_w[i] / ANCS[a][0]);
    float twy = logf(s_h[i] / ANCS[a][1]);
    float wgt = s_wt[i];
    const float* pt = ptxywh + ((size_t)b * HWA + r) * 4;
    float s0 = 1.0f / (1.0f + expf(-pt[0]));
    float s1 = 1.0f / (1.0f + expf(-pt[1]));
    s0 = fminf(fmaxf(s0, BCE_EPS), 1.0f - BCE_EPS);
    s1 = fminf(fmaxf(s1, BCE_EPS), 1.0f - BCE_EPS);
    float b0 = -(tx * logf(s0) + (1.0f - tx) * logf(1.0f - s0));
    float b1 = -(ty * logf(s1) + (1.0f - ty) * logf(1.0f - s1));
    txty_sum += (b0 + b1) * wgt;
    float d2 = pt[2] - twx, d3 = pt[3] - twy;
    twth_sum += (d2 * d2 + d3 * d3) * wgt;
  }

  // ---- block reduce 7 partials, write per-batch row ----
  float v[7] = {sum_pos, sum_neg, cls_sum, txty_sum, twth_sum,
                (float)cnt_pos, (float)cnt_neg};
  int lane = tid & 63, wv = tid >> 6;
  for (int m = 0; m < 7; ++m) {
    float x = v[m];
    for (int o = 32; o > 0; o >>= 1) x += __shfl_down(x, o, 64);
    if (lane == 0) red[wv][m] = x;
  }
  __syncthreads();
  if (tid == 0) {
    float* w = part + b * 8;
    for (int m = 0; m < 7; ++m)
      w[m] = red[0][m] + red[1][m] + red[2][m] + red[3][m];
  }
}

__global__ void yolo_final(const float* __restrict__ part,
                           float* __restrict__ out) {
  int t = threadIdx.x;  // 64 threads, one wave
  float sp = 0, sn = 0, cp = 0, cn = 0, lc = 0, lt = 0, lw = 0;
  if (t < BATCH) {
    const float* w = part + t * 8;
    sp = w[0]; sn = w[1]; cp = w[5]; cn = w[6];
    float np = fmaxf(w[5], FP16_EPS);
    lc = w[2] / np; lt = w[3] / np; lw = w[4] / np;
  }
  for (int o = 32; o > 0; o >>= 1) {
    sp += __shfl_down(sp, o, 64);
    sn += __shfl_down(sn, o, 64);
    cp += __shfl_down(cp, o, 64);
    cn += __shfl_down(cn, o, 64);
    lc += __shfl_down(lc, o, 64);
    lt += __shfl_down(lt, o, 64);
    lw += __shfl_down(lw, o, 64);
  }
  if (t == 0) {
    // l_conf_pos + l_conf_neg + l_cls + l_txty + l_twth
    out[0] = sp / cp * 30.0f + sn / cn * 30.0f +
             (lc + lt + lw) * (1.0f / (float)BATCH);
  }
}

extern "C" void kernel_launch(void* const* d_in, const int* in_sizes, int n_in,
                              void* d_out, int out_size, void* d_ws,
                              size_t ws_size, hipStream_t stream) {
  const float* pconf  = (const float*)d_in[0];
  const float* pcls   = (const float*)d_in[1];
  const float* ptxywh = (const float*)d_in[2];
  const float* gbox   = (const float*)d_in[3];
  const int*   glab   = (const int*)d_in[4];
  float* part = (float*)d_ws;  // [BATCH, 8] floats

  yolo_main<<<BATCH, 256, 0, stream>>>(pconf, pcls, ptxywh, gbox, glab, part);
  yolo_final<<<1, 64, 0, stream>>>(part, (float*)d_out);
}

// Round 2
// 171.928 us; speedup vs baseline: 1.0162x; 1.0162x over previous
//
#include <hip/hip_runtime.h>
#include <math.h>

#define BATCH 32
#define NGT 20
#define HWA 10647
#define NCLS 80
#define FP16_EPS 0.0009765625f
#define BCE_EPS 1e-6f

__device__ __constant__ float ANCS[9][2] = {
    {0.024f, 0.031f}, {0.038f, 0.072f}, {0.079f, 0.055f},
    {0.072f, 0.147f}, {0.149f, 0.108f}, {0.142f, 0.286f},
    {0.279f, 0.216f}, {0.375f, 0.476f}, {0.897f, 0.784f}};

// Fast device math: v_exp_f32 / v_log_f32 / v_rcp_f32 based. Error budget:
// threshold is 1.79 on a ~89.5 scalar; these are ~1e-7 rel-err -> final
// error ~1e-4. (Round 1 with precise libm had absmax 0.0.)
__device__ __forceinline__ float fexp(float x) { return __expf(x); }
__device__ __forceinline__ float flog(float x) { return __logf(x); }
__device__ __forceinline__ float fsig(float x) {
  return __builtin_amdgcn_rcpf(1.0f + __expf(-x));
}

// Matching state per HWA row, packed into one int resolved by atomicMax:
//   bits [31:16] = priority (2p+1 for the "-1" col0 write, 2p+2 for the
//                  positive full-row write at scan step p)
//   bit  [15]    = is-positive-write
//   bits [7:0]   = rec = i*9 + a  (GT index i, anchor id a)
// cell == 0 <=> never written <=> gconf == 0 (negative row).
// Priorities strictly increase in the reference's sequential scan order, so
// atomicMax reproduces last-writer-wins exactly (verified: absmax 0.0 in R1).

__global__ __launch_bounds__(256) void yolo_main(
    const float* __restrict__ pconf,   // [B, HWA, 1]
    const float* __restrict__ pcls,    // [B, HWA, 80]
    const float* __restrict__ ptxywh,  // [B, HWA, 4]
    const float* __restrict__ gbox,    // [B, NGT, 4]
    const int* __restrict__ glab,      // [B, NGT]
    float* __restrict__ part)          // [B, 8] partials
{
  const int b = blockIdx.x;
  const int tid = threadIdx.x;

  __shared__ int cell[HWA];
  __shared__ int pos_list[256];
  __shared__ float s_cx[NGT], s_cy[NGT], s_w[NGT], s_h[NGT], s_wt[NGT];
  __shared__ int s_a[NGT], s_lab[NGT], s_idx[NGT][3];
  __shared__ int s_np;
  __shared__ float red[4][8];

  // ---- init + per-GT precompute (same f32 decision ops as reference) ----
  for (int r = tid; r < HWA; r += 256) cell[r] = 0;
  if (tid == 0) s_np = 0;
  if (tid < NGT) {
    const float* gb = gbox + (b * NGT + tid) * 4;
    float l = gb[0], t = gb[1], r = gb[2], bo = gb[3];
    float cx = (l + r) * 0.5f, cy = (t + bo) * 0.5f;
    float w = r - l, h = bo - t;
    s_cx[tid] = cx; s_cy[tid] = cy; s_w[tid] = w; s_h[tid] = h;
    s_wt[tid] = 2.0f - w * h;
    s_lab[tid] = glab[b * NGT + tid];
    // argmax over 9 ratios: keep precise division here (decision bits).
    float best = -1e30f; int bi = 0;
    for (int a = 0; a < 9; ++a) {
      float inter = fminf(w, ANCS[a][0]) * fminf(h, ANCS[a][1]);
      float uni = w * h + ANCS[a][0] * ANCS[a][1] - inter;
      float ratio = inter / uni;
      if (ratio > best) { best = ratio; bi = a; }  // first max == argmax
    }
    s_a[tid] = bi;
    const int GR[3] = {52, 26, 13};
    const int OF[3] = {0, 2704, 3380};
    for (int j = 0; j < 3; ++j) {
      int col = (int)(cx * (float)GR[j]);   // trunc, matches astype(int32)
      int row = (int)(cy * (float)GR[j]);
      s_idx[tid][j] = (OF[j] + row * GR[j] + col) * 3;
    }
  }
  __syncthreads();

  // ---- the 400-step scan, parallelized via priority atomicMax ----
  for (int p = tid; p < NGT * NGT; p += 256) {
    int i = p / NGT, k = p - i * NGT;
    int a = s_a[k];
    int ceng = a / 3;
    int pn = (2 * p + 1) << 16;
    int pp = ((2 * p + 2) << 16) | (1 << 15) | (i * 9 + a);
    for (int j = 0; j < 3; ++j) {
      int idx = s_idx[i][j];
      atomicMax(&cell[idx], pn);
      atomicMax(&cell[idx + 1], pn);
      atomicMax(&cell[idx + 2], pn);
      if (ceng == j) atomicMax(&cell[idx + (a - ceng * 3)], pp);
    }
  }
  __syncthreads();

  // ---- dense pconf pass + positive-row compaction ----
  float sum_pos = 0.f, sum_neg = 0.f;
  int cnt_pos = 0, cnt_neg = 0;
  for (int r = tid; r < HWA; r += 256) {
    int c = cell[r];
    float x = pconf[(size_t)b * HWA + r];
    float s = fsig(x);
    if (c == 0) {                      // gconf == 0
      sum_neg += s * s; cnt_neg++;
    } else if (c & (1 << 15)) {        // gconf == 1
      float d = s - 1.0f; sum_pos += d * d; cnt_pos++;
      int slot = atomicAdd(&s_np, 1);
      if (slot < 256) pos_list[slot] = ((c & 0xFF) << 16) | r;
    }                                  // else gconf == -1: ignored
  }
  __syncthreads();
  int P = s_np;

  // ---- sparse class BCE over positive rows (P*80 work items) ----
  float cls_sum = 0.f;
  for (int idx = tid; idx < P * NCLS; idx += 256) {
    int pr = idx / NCLS, c = idx - pr * NCLS;
    int pk = pos_list[pr];
    int r = pk & 0xFFFF, rec = pk >> 16;
    int i = rec / 9;
    int lab = s_lab[i] - 1;
    float x = pcls[((size_t)b * HWA + r) * NCLS + c];
    float s = fsig(x);
    s = fminf(fmaxf(s, BCE_EPS), 1.0f - BCE_EPS);
    float g = (c == lab) ? 1.0f : 0.0f;
    cls_sum += -(g * flog(s) + (1.0f - g) * flog(1.0f - s));
  }

  // ---- sparse txty (BCE) + twth (L2) over positive rows ----
  float txty_sum = 0.f, twth_sum = 0.f;
  for (int q = tid; q < P; q += 256) {
    int pk = pos_list[q];
    int r = pk & 0xFFFF, rec = pk >> 16;
    int i = rec / 9, a = rec - i * 9;
    int ceng = a / 3;
    const int GR[3] = {52, 26, 13};
    float grid = (float)GR[ceng];
    float cx = s_cx[i], cy = s_cy[i];
    int col = (int)(cx * grid), row = (int)(cy * grid);
    float tx = (cx - (float)col / grid) * grid;
    float ty = (cy - (float)row / grid) * grid;
    float twx = flog(s_w[i] / ANCS[a][0]);
    float twy = flog(s_h[i] / ANCS[a][1]);
    float wgt = s_wt[i];
    const float* pt = ptxywh + ((size_t)b * HWA + r) * 4;
    float s0 = fsig(pt[0]);
    float s1 = fsig(pt[1]);
    s0 = fminf(fmaxf(s0, BCE_EPS), 1.0f - BCE_EPS);
    s1 = fminf(fmaxf(s1, BCE_EPS), 1.0f - BCE_EPS);
    float b0 = -(tx * flog(s0) + (1.0f - tx) * flog(1.0f - s0));
    float b1 = -(ty * flog(s1) + (1.0f - ty) * flog(1.0f - s1));
    txty_sum += (b0 + b1) * wgt;
    float d2 = pt[2] - twx, d3 = pt[3] - twy;
    twth_sum += (d2 * d2 + d3 * d3) * wgt;
  }

  // ---- block reduce 7 partials, write per-batch row ----
  float v[7] = {sum_pos, sum_neg, cls_sum, txty_sum, twth_sum,
                (float)cnt_pos, (float)cnt_neg};
  int lane = tid & 63, wv = tid >> 6;
  for (int m = 0; m < 7; ++m) {
    float x = v[m];
    for (int o = 32; o > 0; o >>= 1) x += __shfl_down(x, o, 64);
    if (lane == 0) red[wv][m] = x;
  }
  __syncthreads();
  if (tid == 0) {
    float* w = part + b * 8;
    for (int m = 0; m < 7; ++m)
      w[m] = red[0][m] + red[1][m] + red[2][m] + red[3][m];
  }
}

__global__ void yolo_final(const float* __restrict__ part,
                           float* __restrict__ out) {
  int t = threadIdx.x;  // 64 threads, one wave
  float sp = 0, sn = 0, cp = 0, cn = 0, lc = 0, lt = 0, lw = 0;
  if (t < BATCH) {
    const float* w = part + t * 8;
    sp = w[0]; sn = w[1]; cp = w[5]; cn = w[6];
    float np = fmaxf(w[5], FP16_EPS);
    float rnp = 1.0f / np;
    lc = w[2] * rnp; lt = w[3] * rnp; lw = w[4] * rnp;
  }
  for (int o = 32; o > 0; o >>= 1) {
    sp += __shfl_down(sp, o, 64);
    sn += __shfl_down(sn, o, 64);
    cp += __shfl_down(cp, o, 64);
    cn += __shfl_down(cn, o, 64);
    lc += __shfl_down(lc, o, 64);
    lt += __shfl_down(lt, o, 64);
    lw += __shfl_down(lw, o, 64);
  }
  if (t == 0) {
    // l_conf_pos + l_conf_neg + l_cls + l_txty + l_twth
    out[0] = sp / cp * 30.0f + sn / cn * 30.0f +
             (lc + lt + lw) * (1.0f / (float)BATCH);
  }
}

extern "C" void kernel_launch(void* const* d_in, const int* in_sizes, int n_in,
                              void* d_out, int out_size, void* d_ws,
                              size_t ws_size, hipStream_t stream) {
  const float* pconf  = (const float*)d_in[0];
  const float* pcls   = (const float*)d_in[1];
  const float* ptxywh = (const float*)d_in[2];
  const float* gbox   = (const float*)d_in[3];
  const int*   glab   = (const int*)d_in[4];
  float* part = (float*)d_ws;  // [BATCH, 8] floats

  yolo_main<<<BATCH, 256, 0, stream>>>(pconf, pcls, ptxywh, gbox, glab, part);
  yolo_final<<<1, 64, 0, stream>>>(part, (float*)d_out);
}

// Round 3
// 155.065 us; speedup vs baseline: 1.1267x; 1.1087x over previous
//
#include <hip/hip_runtime.h>
#include <math.h>

#define BATCH 32
#define NSLICE 8            // blocks per batch; grid = BATCH*NSLICE = 256 CUs
#define SLICE_LEN 1331      // ceil(HWA/NSLICE); 8*1331 = 10648 >= 10647
#define NGT 20
#define HWA 10647
#define NCLS 80
#define FP16_EPS 0.0009765625f
#define BCE_EPS 1e-6f

__device__ __constant__ float ANCS[9][2] = {
    {0.024f, 0.031f}, {0.038f, 0.072f}, {0.079f, 0.055f},
    {0.072f, 0.147f}, {0.149f, 0.108f}, {0.142f, 0.286f},
    {0.279f, 0.216f}, {0.375f, 0.476f}, {0.897f, 0.784f}};

// Fast device math (v_exp/v_log/v_rcp). R1 precise libm gave absmax 0.0;
// R2 with these still gave absmax 0.0 vs threshold 1.79 — huge slack.
__device__ __forceinline__ float flog(float x) { return __logf(x); }
__device__ __forceinline__ float fsig(float x) {
  return __builtin_amdgcn_rcpf(1.0f + __expf(-x));
}

// Matching state per HWA row, packed into one int resolved by atomicMax:
//   bits [31:16] = priority (2p+1 for the "-1" col0 write, 2p+2 for the
//                  positive full-row write at scan step p)
//   bit  [15]    = is-positive-write
//   bits [7:0]   = rec = i*9 + a  (GT index i, anchor id a)
// cell == 0 <=> never written <=> gconf == 0 (negative row).
// atomicMax reproduces the reference scan's last-writer-wins exactly
// (verified absmax 0.0 in R1/R2). Matching is replicated per slice-block —
// max is order-independent, so every replica computes identical state.

__global__ __launch_bounds__(256) void yolo_main(
    const float* __restrict__ pconf,   // [B, HWA, 1]
    const float* __restrict__ pcls,    // [B, HWA, 80]
    const float* __restrict__ ptxywh,  // [B, HWA, 4]
    const float* __restrict__ gbox,    // [B, NGT, 4]
    const int* __restrict__ glab,      // [B, NGT]
    float* __restrict__ part)          // [B*NSLICE, 8] partials
{
  const int b = blockIdx.x;        // batch
  const int sl = blockIdx.y;       // slice of HWA
  const int tid = threadIdx.x;

  __shared__ int cell[HWA];
  __shared__ int pos_list[256];
  __shared__ float s_cx[NGT], s_cy[NGT], s_w[NGT], s_h[NGT], s_wt[NGT];
  __shared__ int s_a[NGT], s_lab[NGT], s_idx[NGT][3];
  __shared__ int s_np;
  __shared__ float red[4][8];

  // ---- init + per-GT precompute (same f32 decision ops as reference) ----
  for (int r = tid; r < HWA; r += 256) cell[r] = 0;
  if (tid == 0) s_np = 0;
  if (tid < NGT) {
    const float* gb = gbox + (b * NGT + tid) * 4;
    float l = gb[0], t = gb[1], r = gb[2], bo = gb[3];
    float cx = (l + r) * 0.5f, cy = (t + bo) * 0.5f;
    float w = r - l, h = bo - t;
    s_cx[tid] = cx; s_cy[tid] = cy; s_w[tid] = w; s_h[tid] = h;
    s_wt[tid] = 2.0f - w * h;
    s_lab[tid] = glab[b * NGT + tid];
    // argmax over 9 ratios: precise division (decision bits must match).
    float best = -1e30f; int bi = 0;
    for (int a = 0; a < 9; ++a) {
      float inter = fminf(w, ANCS[a][0]) * fminf(h, ANCS[a][1]);
      float uni = w * h + ANCS[a][0] * ANCS[a][1] - inter;
      float ratio = inter / uni;
      if (ratio > best) { best = ratio; bi = a; }  // first max == argmax
    }
    s_a[tid] = bi;
    const int GR[3] = {52, 26, 13};
    const int OF[3] = {0, 2704, 3380};
    for (int j = 0; j < 3; ++j) {
      int col = (int)(cx * (float)GR[j]);   // trunc, matches astype(int32)
      int row = (int)(cy * (float)GR[j]);
      s_idx[tid][j] = (OF[j] + row * GR[j] + col) * 3;
    }
  }
  __syncthreads();

  // ---- the 400-step scan, parallelized via priority atomicMax ----
  for (int p = tid; p < NGT * NGT; p += 256) {
    int i = p / NGT, k = p - i * NGT;
    int a = s_a[k];
    int ceng = a / 3;
    int pn = (2 * p + 1) << 16;
    int pp = ((2 * p + 2) << 16) | (1 << 15) | (i * 9 + a);
    for (int j = 0; j < 3; ++j) {
      int idx = s_idx[i][j];
      atomicMax(&cell[idx], pn);
      atomicMax(&cell[idx + 1], pn);
      atomicMax(&cell[idx + 2], pn);
      if (ceng == j) atomicMax(&cell[idx + (a - ceng * 3)], pp);
    }
  }
  __syncthreads();

  // ---- dense pconf pass over this block's slice + positive compaction ----
  const int r0 = sl * SLICE_LEN;
  const int r1 = min(r0 + SLICE_LEN, HWA);
  float sum_pos = 0.f, sum_neg = 0.f;
  int cnt_pos = 0, cnt_neg = 0;
  for (int r = r0 + tid; r < r1; r += 256) {
    int c = cell[r];
    float x = pconf[(size_t)b * HWA + r];
    float s = fsig(x);
    if (c == 0) {                      // gconf == 0
      sum_neg += s * s; cnt_neg++;
    } else if (c & (1 << 15)) {        // gconf == 1
      float d = s - 1.0f; sum_pos += d * d; cnt_pos++;
      int slot = atomicAdd(&s_np, 1);
      if (slot < 256) pos_list[slot] = ((c & 0xFF) << 16) | r;
    }                                  // else gconf == -1: ignored
  }
  __syncthreads();
  int P = s_np;

  // ---- sparse class BCE over this slice's positive rows ----
  float cls_sum = 0.f;
  for (int idx = tid; idx < P * NCLS; idx += 256) {
    int pr = idx / NCLS, c = idx - pr * NCLS;
    int pk = pos_list[pr];
    int r = pk & 0xFFFF, rec = pk >> 16;
    int i = rec / 9;
    int lab = s_lab[i] - 1;
    float x = pcls[((size_t)b * HWA + r) * NCLS + c];
    float s = fsig(x);
    s = fminf(fmaxf(s, BCE_EPS), 1.0f - BCE_EPS);
    float g = (c == lab) ? 1.0f : 0.0f;
    cls_sum += -(g * flog(s) + (1.0f - g) * flog(1.0f - s));
  }

  // ---- sparse txty (BCE) + twth (L2) over this slice's positive rows ----
  float txty_sum = 0.f, twth_sum = 0.f;
  for (int q = tid; q < P; q += 256) {
    int pk = pos_list[q];
    int r = pk & 0xFFFF, rec = pk >> 16;
    int i = rec / 9, a = rec - i * 9;
    int ceng = a / 3;
    const int GR[3] = {52, 26, 13};
    float grid = (float)GR[ceng];
    float cx = s_cx[i], cy = s_cy[i];
    int col = (int)(cx * grid), row = (int)(cy * grid);
    float tx = (cx - (float)col / grid) * grid;
    float ty = (cy - (float)row / grid) * grid;
    float twx = flog(s_w[i] / ANCS[a][0]);
    float twy = flog(s_h[i] / ANCS[a][1]);
    float wgt = s_wt[i];
    const float* pt = ptxywh + ((size_t)b * HWA + r) * 4;
    float s0 = fsig(pt[0]);
    float s1 = fsig(pt[1]);
    s0 = fminf(fmaxf(s0, BCE_EPS), 1.0f - BCE_EPS);
    s1 = fminf(fmaxf(s1, BCE_EPS), 1.0f - BCE_EPS);
    float b0 = -(tx * flog(s0) + (1.0f - tx) * flog(1.0f - s0));
    float b1 = -(ty * flog(s1) + (1.0f - ty) * flog(1.0f - s1));
    txty_sum += (b0 + b1) * wgt;
    float d2 = pt[2] - twx, d3 = pt[3] - twy;
    twth_sum += (d2 * d2 + d3 * d3) * wgt;
  }

  // ---- block reduce 7 partials, write this (batch, slice) row ----
  float v[7] = {sum_pos, sum_neg, cls_sum, txty_sum, twth_sum,
                (float)cnt_pos, (float)cnt_neg};
  int lane = tid & 63, wv = tid >> 6;
  for (int m = 0; m < 7; ++m) {
    float x = v[m];
    for (int o = 32; o > 0; o >>= 1) x += __shfl_down(x, o, 64);
    if (lane == 0) red[wv][m] = x;
  }
  __syncthreads();
  if (tid == 0) {
    float* w = part + (b * NSLICE + sl) * 8;
    for (int m = 0; m < 7; ++m)
      w[m] = red[0][m] + red[1][m] + red[2][m] + red[3][m];
  }
}

__global__ __launch_bounds__(256) void yolo_final(
    const float* __restrict__ part, float* __restrict__ out) {
  const int t = threadIdx.x;           // 256 threads: row t = (b = t>>3, s = t&7)
  __shared__ float sb[BATCH][8];
  float v[7];
  const float* w = part + t * 8;
#pragma unroll
  for (int m = 0; m < 7; ++m) v[m] = w[m];
  // reduce the 8 slices of each batch (consecutive 8 lanes, same wave)
#pragma unroll
  for (int o = 4; o > 0; o >>= 1)
#pragma unroll
    for (int m = 0; m < 7; ++m) v[m] += __shfl_down(v[m], o, 8);
  if ((t & 7) == 0) {
    int b = t >> 3;
    float np = fmaxf(v[5], FP16_EPS);
    float rnp = 1.0f / np;
    sb[b][0] = v[0];              // sum_pos
    sb[b][1] = v[1];              // sum_neg
    sb[b][2] = v[5];              // cnt_pos
    sb[b][3] = v[6];              // cnt_neg
    sb[b][4] = v[2] * rnp;        // l_cls_b
    sb[b][5] = v[3] * rnp;        // l_txty_b
    sb[b][6] = v[4] * rnp;        // l_twth_b
  }
  __syncthreads();
  if (t < 32) {
    float u[7];
#pragma unroll
    for (int m = 0; m < 7; ++m) u[m] = sb[t][m];
#pragma unroll
    for (int o = 16; o > 0; o >>= 1)
#pragma unroll
      for (int m = 0; m < 7; ++m) u[m] += __shfl_down(u[m], o, 32);
    if (t == 0) {
      out[0] = u[0] / u[2] * 30.0f + u[1] / u[3] * 30.0f +
               (u[4] + u[5] + u[6]) * (1.0f / (float)BATCH);
    }
  }
}

extern "C" void kernel_launch(void* const* d_in, const int* in_sizes, int n_in,
                              void* d_out, int out_size, void* d_ws,
                              size_t ws_size, hipStream_t stream) {
  const float* pconf  = (const float*)d_in[0];
  const float* pcls   = (const float*)d_in[1];
  const float* ptxywh = (const float*)d_in[2];
  const float* gbox   = (const float*)d_in[3];
  const int*   glab   = (const int*)d_in[4];
  float* part = (float*)d_ws;  // [BATCH*NSLICE, 8] floats = 8 KB

  dim3 grid(BATCH, NSLICE);
  yolo_main<<<grid, 256, 0, stream>>>(pconf, pcls, ptxywh, gbox, glab, part);
  yolo_final<<<1, 256, 0, stream>>>(part, (float*)d_out);
}

// Round 4
// 154.896 us; speedup vs baseline: 1.1280x; 1.0011x over previous
//
#include <hip/hip_runtime.h>
#include <math.h>

#define BATCH 32
#define NSLICE 16           // blocks per batch; grid = 32*16 = 512 (2/CU)
#define SLICE_LEN 666       // ceil(HWA/NSLICE); 16*666 = 10656 >= 10647
#define NGT 20
#define HWA 10647
#define NCLS 80
#define FP16_EPS 0.0009765625f
#define BCE_EPS 1e-6f

__device__ __constant__ float ANCS[9][2] = {
    {0.024f, 0.031f}, {0.038f, 0.072f}, {0.079f, 0.055f},
    {0.072f, 0.147f}, {0.149f, 0.108f}, {0.142f, 0.286f},
    {0.279f, 0.216f}, {0.375f, 0.476f}, {0.897f, 0.784f}};

// Fast device math (v_exp/v_log/v_rcp). R2/R3 with these gave absmax 0.0
// vs threshold 1.79 — huge slack.
__device__ __forceinline__ float flog(float x) { return __logf(x); }
__device__ __forceinline__ float fsig(float x) {
  return __builtin_amdgcn_rcpf(1.0f + __expf(-x));
}

// Matching state per HWA row, packed into one int resolved by atomicMax:
//   bits [31:16] = priority (2p+1 for the "-1" col0 write, 2p+2 for the
//                  positive full-row write at scan step p)
//   bit  [15]    = is-positive-write
//   bits [7:0]   = rec = i*9 + a  (GT index i, anchor id a)
// cell == 0 <=> never written <=> gconf == 0 (negative row).
// atomicMax reproduces the reference scan's last-writer-wins exactly
// (verified absmax 0.0 in R1-R3). Matching is replicated per slice-block,
// but each block keeps only its slice's cells: every scan write targets a
// 3-cell window [idx, idx+2], so out-of-slice writes (never read) are
// simply predicated away — per-slice state is bit-identical to the full
// array version.

__global__ __launch_bounds__(256) void yolo_main(
    const float* __restrict__ pconf,   // [B, HWA, 1]
    const float* __restrict__ pcls,    // [B, HWA, 80]
    const float* __restrict__ ptxywh,  // [B, HWA, 4]
    const float* __restrict__ gbox,    // [B, NGT, 4]
    const int* __restrict__ glab,      // [B, NGT]
    float* __restrict__ part)          // [B*NSLICE, 8] partials
{
  const int b = blockIdx.x;        // batch
  const int sl = blockIdx.y;       // slice of HWA
  const int tid = threadIdx.x;
  const int r0 = sl * SLICE_LEN;
  const int r1 = min(r0 + SLICE_LEN, HWA);

  __shared__ int cell[SLICE_LEN];
  __shared__ int pos_list[256];
  __shared__ float s_cx[NGT], s_cy[NGT], s_w[NGT], s_h[NGT], s_wt[NGT];
  __shared__ int s_a[NGT], s_lab[NGT], s_idx[NGT][3];
  __shared__ int s_np;
  __shared__ float red[4][8];

  // ---- init + per-GT precompute (same f32 decision ops as reference) ----
  for (int r = tid; r < SLICE_LEN; r += 256) cell[r] = 0;
  if (tid == 0) s_np = 0;
  if (tid < NGT) {
    const float* gb = gbox + (b * NGT + tid) * 4;
    float l = gb[0], t = gb[1], r = gb[2], bo = gb[3];
    float cx = (l + r) * 0.5f, cy = (t + bo) * 0.5f;
    float w = r - l, h = bo - t;
    s_cx[tid] = cx; s_cy[tid] = cy; s_w[tid] = w; s_h[tid] = h;
    s_wt[tid] = 2.0f - w * h;
    s_lab[tid] = glab[b * NGT + tid];
    // argmax over 9 ratios: precise division (decision bits must match).
    float best = -1e30f; int bi = 0;
    for (int a = 0; a < 9; ++a) {
      float inter = fminf(w, ANCS[a][0]) * fminf(h, ANCS[a][1]);
      float uni = w * h + ANCS[a][0] * ANCS[a][1] - inter;
      float ratio = inter / uni;
      if (ratio > best) { best = ratio; bi = a; }  // first max == argmax
    }
    s_a[tid] = bi;
    const int GR[3] = {52, 26, 13};
    const int OF[3] = {0, 2704, 3380};
    for (int j = 0; j < 3; ++j) {
      int col = (int)(cx * (float)GR[j]);   // trunc, matches astype(int32)
      int row = (int)(cy * (float)GR[j]);
      s_idx[tid][j] = (OF[j] + row * GR[j] + col) * 3;
    }
  }
  __syncthreads();

  // ---- the 400-step scan, parallelized via priority atomicMax,
  //      predicated to this block's slice ----
  for (int p = tid; p < NGT * NGT; p += 256) {
    int i = p / NGT, k = p - i * NGT;
    int a = s_a[k];
    int ceng = a / 3;
    int pn = (2 * p + 1) << 16;
    int pp = ((2 * p + 2) << 16) | (1 << 15) | (i * 9 + a);
    for (int j = 0; j < 3; ++j) {
      int idx = s_idx[i][j];
      if (idx + 2 >= r0 && idx < r1) {
#pragma unroll
        for (int d = 0; d < 3; ++d) {
          int t = idx + d;
          if (t >= r0 && t < r1) atomicMax(&cell[t - r0], pn);
        }
      }
      if (ceng == j) {
        int t = idx + (a - ceng * 3);
        if (t >= r0 && t < r1) atomicMax(&cell[t - r0], pp);
      }
    }
  }
  __syncthreads();

  // ---- dense pconf pass over this block's slice + positive compaction ----
  float sum_pos = 0.f, sum_neg = 0.f;
  int cnt_pos = 0, cnt_neg = 0;
  for (int r = r0 + tid; r < r1; r += 256) {
    int c = cell[r - r0];
    float x = pconf[(size_t)b * HWA + r];
    float s = fsig(x);
    if (c == 0) {                      // gconf == 0
      sum_neg += s * s; cnt_neg++;
    } else if (c & (1 << 15)) {        // gconf == 1
      float d = s - 1.0f; sum_pos += d * d; cnt_pos++;
      int slot = atomicAdd(&s_np, 1);
      if (slot < 256) pos_list[slot] = ((c & 0xFF) << 16) | r;
    }                                  // else gconf == -1: ignored
  }
  __syncthreads();
  int P = s_np;

  // ---- sparse class BCE over this slice's positive rows ----
  float cls_sum = 0.f;
  for (int idx = tid; idx < P * NCLS; idx += 256) {
    int pr = idx / NCLS, c = idx - pr * NCLS;
    int pk = pos_list[pr];
    int r = pk & 0xFFFF, rec = pk >> 16;
    int i = rec / 9;
    int lab = s_lab[i] - 1;
    float x = pcls[((size_t)b * HWA + r) * NCLS + c];
    float s = fsig(x);
    s = fminf(fmaxf(s, BCE_EPS), 1.0f - BCE_EPS);
    float g = (c == lab) ? 1.0f : 0.0f;
    cls_sum += -(g * flog(s) + (1.0f - g) * flog(1.0f - s));
  }

  // ---- sparse txty (BCE) + twth (L2) over this slice's positive rows ----
  float txty_sum = 0.f, twth_sum = 0.f;
  for (int q = tid; q < P; q += 256) {
    int pk = pos_list[q];
    int r = pk & 0xFFFF, rec = pk >> 16;
    int i = rec / 9, a = rec - i * 9;
    int ceng = a / 3;
    const int GR[3] = {52, 26, 13};
    float grid = (float)GR[ceng];
    float cx = s_cx[i], cy = s_cy[i];
    int col = (int)(cx * grid), row = (int)(cy * grid);
    float tx = (cx - (float)col / grid) * grid;
    float ty = (cy - (float)row / grid) * grid;
    float twx = flog(s_w[i] / ANCS[a][0]);
    float twy = flog(s_h[i] / ANCS[a][1]);
    float wgt = s_wt[i];
    const float* pt = ptxywh + ((size_t)b * HWA + r) * 4;
    float s0 = fsig(pt[0]);
    float s1 = fsig(pt[1]);
    s0 = fminf(fmaxf(s0, BCE_EPS), 1.0f - BCE_EPS);
    s1 = fminf(fmaxf(s1, BCE_EPS), 1.0f - BCE_EPS);
    float b0 = -(tx * flog(s0) + (1.0f - tx) * flog(1.0f - s0));
    float b1 = -(ty * flog(s1) + (1.0f - ty) * flog(1.0f - s1));
    txty_sum += (b0 + b1) * wgt;
    float d2 = pt[2] - twx, d3 = pt[3] - twy;
    twth_sum += (d2 * d2 + d3 * d3) * wgt;
  }

  // ---- block reduce 7 partials, write this (batch, slice) row ----
  float v[7] = {sum_pos, sum_neg, cls_sum, txty_sum, twth_sum,
                (float)cnt_pos, (float)cnt_neg};
  int lane = tid & 63, wv = tid >> 6;
  for (int m = 0; m < 7; ++m) {
    float x = v[m];
    for (int o = 32; o > 0; o >>= 1) x += __shfl_down(x, o, 64);
    if (lane == 0) red[wv][m] = x;
  }
  __syncthreads();
  if (tid == 0) {
    float* w = part + (b * NSLICE + sl) * 8;
    for (int m = 0; m < 7; ++m)
      w[m] = red[0][m] + red[1][m] + red[2][m] + red[3][m];
  }
}

__global__ __launch_bounds__(512) void yolo_final(
    const float* __restrict__ part, float* __restrict__ out) {
  const int t = threadIdx.x;   // 512 threads: row t = (b = t>>4, s = t&15)
  __shared__ float sb[BATCH][8];
  float v[7];
  const float* w = part + t * 8;
#pragma unroll
  for (int m = 0; m < 7; ++m) v[m] = w[m];
  // reduce the 16 slices of each batch (consecutive 16 lanes, same wave)
#pragma unroll
  for (int o = 8; o > 0; o >>= 1)
#pragma unroll
    for (int m = 0; m < 7; ++m) v[m] += __shfl_down(v[m], o, 16);
  if ((t & 15) == 0) {
    int b = t >> 4;
    float np = fmaxf(v[5], FP16_EPS);
    float rnp = 1.0f / np;
    sb[b][0] = v[0];              // sum_pos
    sb[b][1] = v[1];              // sum_neg
    sb[b][2] = v[5];              // cnt_pos
    sb[b][3] = v[6];              // cnt_neg
    sb[b][4] = v[2] * rnp;        // l_cls_b
    sb[b][5] = v[3] * rnp;        // l_txty_b
    sb[b][6] = v[4] * rnp;        // l_twth_b
  }
  __syncthreads();
  if (t < 32) {
    float u[7];
#pragma unroll
    for (int m = 0; m < 7; ++m) u[m] = sb[t][m];
#pragma unroll
    for (int o = 16; o > 0; o >>= 1)
#pragma unroll
      for (int m = 0; m < 7; ++m) u[m] += __shfl_down(u[m], o, 32);
    if (t == 0) {
      out[0] = u[0] / u[2] * 30.0f + u[1] / u[3] * 30.0f +
               (u[4] + u[5] + u[6]) * (1.0f / (float)BATCH);
    }
  }
}

extern "C" void kernel_launch(void* const* d_in, const int* in_sizes, int n_in,
                              void* d_out, int out_size, void* d_ws,
                              size_t ws_size, hipStream_t stream) {
  const float* pconf  = (const float*)d_in[0];
  const float* pcls   = (const float*)d_in[1];
  const float* ptxywh = (const float*)d_in[2];
  const float* gbox   = (const float*)d_in[3];
  const int*   glab   = (const int*)d_in[4];
  float* part = (float*)d_ws;  // [BATCH*NSLICE, 8] floats = 16 KB

  dim3 grid(BATCH, NSLICE);
  yolo_main<<<grid, 256, 0, stream>>>(pconf, pcls, ptxywh, gbox, glab, part);
  yolo_final<<<1, 512, 0, stream>>>(part, (float*)d_out);
}